// Round 1
// baseline (151.283 us; speedup 1.0000x reference)
//
#include <hip/hip_runtime.h>

// Chamfer loss between pred (2048,8,3) and gt (2048,8,3) fp32 point sets.
// N = 16384 points per side. Output: scalar = mean(min d) both directions.
//
// Plan:
//  k1: init 2*N uint min-slots in ws to +inf bits (ws is poisoned 0xAA each call)
//  k2: brute-force min of squared distance, both directions, atomicMin on uint
//      bits of d2 (valid: d2 >= 0, IEEE non-negative floats order as uints)
//  k3: single-block reduce: sqrt each min-d2, sum all 2*N, divide by N.

#define NPTS   16384
#define RPT    8              // x-points per thread (registers)
#define BLOCK  256
#define XPB    (RPT * BLOCK)  // 2048 x-points per block
#define NXB    (NPTS / XPB)   // 8 x-blocks
#define NSEG   32             // y segments (parallelism: 2*8*32 = 512 blocks)
#define YSEG   (NPTS / NSEG)  // 512 y-points per segment
#define YCHUNK 256            // y-points staged in LDS per chunk

__global__ __launch_bounds__(256) void init_mins(unsigned int* mins) {
    int i = blockIdx.x * blockDim.x + threadIdx.x;
    if (i < 2 * NPTS) mins[i] = 0x7F800000u;  // +inf
}

__global__ __launch_bounds__(BLOCK) void chamfer_min(
        const float* __restrict__ pred, const float* __restrict__ gt,
        unsigned int* __restrict__ mins) {
    const int xb  = blockIdx.x;
    const int ys  = blockIdx.y;
    const int dir = blockIdx.z;
    const float* __restrict__ X = dir ? gt : pred;
    const float* __restrict__ Y = dir ? pred : gt;
    unsigned int* __restrict__ outm = mins + dir * NPTS;
    const int tid = threadIdx.x;

    // Load RPT x-points into registers (once; negligible traffic).
    float xx[RPT], xy[RPT], xz[RPT], mn[RPT];
    const int xbase = xb * XPB;
#pragma unroll
    for (int r = 0; r < RPT; ++r) {
        int xi = xbase + r * BLOCK + tid;
        xx[r] = X[3 * xi + 0];
        xy[r] = X[3 * xi + 1];
        xz[r] = X[3 * xi + 2];
        mn[r] = 3.0e38f;
    }

    __shared__ float4 sh[YCHUNK];  // padded to float4 -> ds_read_b128

    const int y0 = ys * YSEG;
    for (int c = 0; c < YSEG; c += YCHUNK) {
        __syncthreads();
        {   // stage YCHUNK y-points, one per thread
            int yi = y0 + c + tid;
            sh[tid] = make_float4(Y[3 * yi + 0], Y[3 * yi + 1], Y[3 * yi + 2], 0.0f);
        }
        __syncthreads();
#pragma unroll 4
        for (int j = 0; j < YCHUNK; ++j) {
            float4 y = sh[j];  // uniform address -> LDS broadcast, conflict-free
#pragma unroll
            for (int r = 0; r < RPT; ++r) {
                float dx = xx[r] - y.x;
                float dy = xy[r] - y.y;
                float dz = xz[r] - y.z;
                float d2 = dx * dx + dy * dy + dz * dz;  // mul + 2 fma
                mn[r] = fminf(mn[r], d2);
            }
        }
    }

#pragma unroll
    for (int r = 0; r < RPT; ++r) {
        int xi = xbase + r * BLOCK + tid;
        atomicMin(&outm[xi], __float_as_uint(mn[r]));
    }
}

__global__ __launch_bounds__(1024) void chamfer_reduce(
        const unsigned int* __restrict__ mins, float* __restrict__ out) {
    const int tid = threadIdx.x;
    float s = 0.0f;
    for (int i = tid; i < 2 * NPTS; i += 1024)
        s += sqrtf(__uint_as_float(mins[i]));

    // wave (64-lane) shuffle reduce
#pragma unroll
    for (int off = 32; off > 0; off >>= 1)
        s += __shfl_down(s, off, 64);

    __shared__ float part[16];
    if ((tid & 63) == 0) part[tid >> 6] = s;
    __syncthreads();
    if (tid == 0) {
        float t = 0.0f;
#pragma unroll
        for (int w = 0; w < 16; ++w) t += part[w];
        out[0] = t / (float)NPTS;  // mean_p2g + mean_g2p = (sum0+sum1)/N
    }
}

extern "C" void kernel_launch(void* const* d_in, const int* in_sizes, int n_in,
                              void* d_out, int out_size, void* d_ws, size_t ws_size,
                              hipStream_t stream) {
    const float* pred = (const float*)d_in[0];
    const float* gt   = (const float*)d_in[1];
    float* out        = (float*)d_out;
    unsigned int* mins = (unsigned int*)d_ws;  // 2*NPTS uints = 128 KB

    hipLaunchKernelGGL(init_mins, dim3((2 * NPTS + 255) / 256), dim3(256), 0, stream,
                       mins);
    hipLaunchKernelGGL(chamfer_min, dim3(NXB, NSEG, 2), dim3(BLOCK), 0, stream,
                       pred, gt, mins);
    hipLaunchKernelGGL(chamfer_reduce, dim3(1), dim3(1024), 0, stream, mins, out);
}

// Round 2
// 107.166 us; speedup vs baseline: 1.4117x; 1.4117x over previous
//
#include <hip/hip_runtime.h>

// Chamfer loss: pred (2048,8,3) vs gt (2048,8,3) fp32. N=16384 pts/side.
// out = mean(min_m d(x,y)) + mean(min_n d(x,y)); group-mean == global mean.
//
// R2: dot-product expansion -> 4 VALU/pair (3 fma + 1 max):
//   t = x.y - |y|^2/2  (w = -|y|^2/2 staged in LDS float4.w)
//   min_y d2 = |x|^2 - 2*max_y t
// RPT=16 (64 VALU per ds_read_b128), NSEG=128 -> 1024 blocks (4/CU).
//
//  k1: init 2*N uint min slots to +inf bits
//  k2: brute force max(t) per x over a 128-y segment, atomicMin on d2 bits
//  k3: single block: sqrt + sum + /N

#define NPTS   16384
#define RPT    16             // x-points per thread (registers)
#define BLOCK  256
#define XPB    (RPT * BLOCK)  // 4096 x-points per block
#define NXB    (NPTS / XPB)   // 4 x-blocks
#define NSEG   128            // y segments -> 2*4*128 = 1024 blocks
#define YSEG   (NPTS / NSEG)  // 128 y-points per segment (one LDS chunk)

__global__ __launch_bounds__(256) void init_mins(unsigned int* mins) {
    int i = blockIdx.x * blockDim.x + threadIdx.x;
    if (i < 2 * NPTS) mins[i] = 0x7F800000u;  // +inf
}

__global__ __launch_bounds__(BLOCK, 4) void chamfer_min(
        const float* __restrict__ pred, const float* __restrict__ gt,
        unsigned int* __restrict__ mins) {
    const int xb  = blockIdx.x;
    const int ys  = blockIdx.y;
    const int dir = blockIdx.z;
    const float* __restrict__ X = dir ? gt : pred;
    const float* __restrict__ Y = dir ? pred : gt;
    unsigned int* __restrict__ outm = mins + dir * NPTS;
    const int tid = threadIdx.x;

    __shared__ float4 sh[YSEG];  // (yx, yy, yz, -|y|^2/2)

    // stage the y-segment (one chunk for the whole kernel)
    if (tid < YSEG) {
        int yi = ys * YSEG + tid;
        float a = Y[3 * yi + 0], b = Y[3 * yi + 1], c = Y[3 * yi + 2];
        sh[tid] = make_float4(a, b, c, -0.5f * (a * a + b * b + c * c));
    }

    // x-points in registers
    float xx[RPT], xy[RPT], xz[RPT], x2[RPT], mx[RPT];
    const int xbase = xb * XPB;
#pragma unroll
    for (int r = 0; r < RPT; ++r) {
        int xi = xbase + r * BLOCK + tid;
        xx[r] = X[3 * xi + 0];
        xy[r] = X[3 * xi + 1];
        xz[r] = X[3 * xi + 2];
        x2[r] = xx[r] * xx[r] + xy[r] * xy[r] + xz[r] * xz[r];
        mx[r] = -3.0e38f;
    }

    __syncthreads();

#pragma unroll 2
    for (int j = 0; j < YSEG; ++j) {
        float4 y = sh[j];  // uniform address -> broadcast, conflict-free
#pragma unroll
        for (int r = 0; r < RPT; ++r) {
            float t = fmaf(xz[r], y.z, y.w);   // xz*yz - |y|^2/2
            t = fmaf(xy[r], y.y, t);
            t = fmaf(xx[r], y.x, t);           // x.y - |y|^2/2
            mx[r] = fmaxf(mx[r], t);
        }
    }

#pragma unroll
    for (int r = 0; r < RPT; ++r) {
        int xi = xbase + r * BLOCK + tid;
        float d2 = fmaxf(fmaf(-2.0f, mx[r], x2[r]), 0.0f);  // |x|^2 - 2*max t
        atomicMin(&outm[xi], __float_as_uint(d2));
    }
}

__global__ __launch_bounds__(1024) void chamfer_reduce(
        const unsigned int* __restrict__ mins, float* __restrict__ out) {
    const int tid = threadIdx.x;
    float s = 0.0f;
    for (int i = tid; i < 2 * NPTS; i += 1024)
        s += sqrtf(__uint_as_float(mins[i]));

#pragma unroll
    for (int off = 32; off > 0; off >>= 1)
        s += __shfl_down(s, off, 64);

    __shared__ float part[16];
    if ((tid & 63) == 0) part[tid >> 6] = s;
    __syncthreads();
    if (tid == 0) {
        float t = 0.0f;
#pragma unroll
        for (int w = 0; w < 16; ++w) t += part[w];
        out[0] = t / (float)NPTS;  // (sum_p2g + sum_g2p)/N
    }
}

extern "C" void kernel_launch(void* const* d_in, const int* in_sizes, int n_in,
                              void* d_out, int out_size, void* d_ws, size_t ws_size,
                              hipStream_t stream) {
    const float* pred = (const float*)d_in[0];
    const float* gt   = (const float*)d_in[1];
    float* out        = (float*)d_out;
    unsigned int* mins = (unsigned int*)d_ws;  // 2*NPTS uints = 128 KB

    hipLaunchKernelGGL(init_mins, dim3((2 * NPTS + 255) / 256), dim3(256), 0, stream,
                       mins);
    hipLaunchKernelGGL(chamfer_min, dim3(NXB, NSEG, 2), dim3(BLOCK), 0, stream,
                       pred, gt, mins);
    hipLaunchKernelGGL(chamfer_reduce, dim3(1), dim3(1024), 0, stream, mins, out);
}

// Round 3
// 99.056 us; speedup vs baseline: 1.5272x; 1.0819x over previous
//
#include <hip/hip_runtime.h>

// Chamfer loss: pred (2048,8,3) vs gt (2048,8,3) fp32. N=16384 pts/side.
// out = mean(min_m d) + mean(min_n d); 8-corner group-mean == global mean.
//
// R3:
//  - packed fp32: x-points processed as float2 ext-vectors so the 3 FMAs/pair
//    lower to v_pk_fma_f32 (VOP3P, 2 FLOP-lanes/instr) -> 5 instr per 2 pairs
//    instead of 8. (157 TF fp32 spec is only reachable packed.)
//  - parallel reduce: 64 blocks, wave shuffle-reduce, scaled atomicAdd into
//    out[0] (R2's single-block reduce serialized ~45 us of cross-XCD loads).
//
//  k1: init 2*N uint min slots to +inf bits, zero out[0]
//  k2: brute-force max(t) per x over a 128-y segment; t = x.y - |y|^2/2 in
//      LDS float4.w; min d2 = |x|^2 - 2*max t; atomicMin on d2 bits
//  k3: sqrt + sum, atomicAdd(out, partial/N)

#define NPTS   16384
#define RPT    16             // x-points per thread (8 float2 lanes)
#define RPT2   (RPT / 2)
#define BLOCK  256
#define XPB    (RPT * BLOCK)  // 4096 x-points per block
#define NXB    (NPTS / XPB)   // 4 x-blocks
#define NSEG   128            // y segments -> 2*4*128 = 1024 blocks (4/CU)
#define YSEG   (NPTS / NSEG)  // 128 y-points per segment (one LDS chunk)

typedef float v2f __attribute__((ext_vector_type(2)));

__global__ __launch_bounds__(256) void init_mins(unsigned int* mins, float* out) {
    int i = blockIdx.x * blockDim.x + threadIdx.x;
    if (i < 2 * NPTS) mins[i] = 0x7F800000u;  // +inf
    if (i == 0) out[0] = 0.0f;
}

__global__ __launch_bounds__(BLOCK, 4) void chamfer_min(
        const float* __restrict__ pred, const float* __restrict__ gt,
        unsigned int* __restrict__ mins) {
    const int xb  = blockIdx.x;
    const int ys  = blockIdx.y;
    const int dir = blockIdx.z;
    const float* __restrict__ X = dir ? gt : pred;
    const float* __restrict__ Y = dir ? pred : gt;
    unsigned int* __restrict__ outm = mins + dir * NPTS;
    const int tid = threadIdx.x;

    __shared__ float4 sh[YSEG];  // (yx, yy, yz, -|y|^2/2)

    if (tid < YSEG) {
        int yi = ys * YSEG + tid;
        float a = Y[3 * yi + 0], b = Y[3 * yi + 1], c = Y[3 * yi + 2];
        sh[tid] = make_float4(a, b, c, -0.5f * (a * a + b * b + c * c));
    }

    // x-points in registers, packed 2-wide (pair r=2k, 2k+1)
    v2f xx[RPT2], xy[RPT2], xz[RPT2], x2[RPT2], mx[RPT2];
    const int xbase = xb * XPB;
#pragma unroll
    for (int k = 0; k < RPT2; ++k) {
        int i0 = xbase + (2 * k + 0) * BLOCK + tid;
        int i1 = xbase + (2 * k + 1) * BLOCK + tid;
        xx[k] = (v2f){X[3 * i0 + 0], X[3 * i1 + 0]};
        xy[k] = (v2f){X[3 * i0 + 1], X[3 * i1 + 1]};
        xz[k] = (v2f){X[3 * i0 + 2], X[3 * i1 + 2]};
        x2[k] = xx[k] * xx[k] + xy[k] * xy[k] + xz[k] * xz[k];
        mx[k] = (v2f){-3.0e38f, -3.0e38f};
    }

    __syncthreads();

#pragma unroll 2
    for (int j = 0; j < YSEG; ++j) {
        float4 y = sh[j];  // uniform address -> broadcast, conflict-free
        v2f yx = (v2f){y.x, y.x};
        v2f yy = (v2f){y.y, y.y};
        v2f yz = (v2f){y.z, y.z};
        v2f yw = (v2f){y.w, y.w};
#pragma unroll
        for (int k = 0; k < RPT2; ++k) {
            v2f t = __builtin_elementwise_fma(xz[k], yz, yw);  // v_pk_fma_f32
            t = __builtin_elementwise_fma(xy[k], yy, t);
            t = __builtin_elementwise_fma(xx[k], yx, t);
            mx[k] = __builtin_elementwise_max(mx[k], t);
        }
    }

#pragma unroll
    for (int k = 0; k < RPT2; ++k) {
        v2f d2 = __builtin_elementwise_max(
            __builtin_elementwise_fma((v2f){-2.0f, -2.0f}, mx[k], x2[k]),
            (v2f){0.0f, 0.0f});
        int i0 = xbase + (2 * k + 0) * BLOCK + tid;
        int i1 = xbase + (2 * k + 1) * BLOCK + tid;
        atomicMin(&outm[i0], __float_as_uint(d2.x));
        atomicMin(&outm[i1], __float_as_uint(d2.y));
    }
}

__global__ __launch_bounds__(256) void chamfer_reduce(
        const unsigned int* __restrict__ mins, float* __restrict__ out) {
    const int gid = blockIdx.x * 256 + threadIdx.x;  // 64 blocks x 256
    float s = 0.0f;
#pragma unroll
    for (int i = 0; i < 2; ++i)  // 2*NPTS / (64*256) = 2 elements/thread
        s += sqrtf(__uint_as_float(mins[gid + i * 64 * 256]));

#pragma unroll
    for (int off = 32; off > 0; off >>= 1)
        s += __shfl_down(s, off, 64);

    if ((threadIdx.x & 63) == 0)
        atomicAdd(out, s * (1.0f / (float)NPTS));  // (sum0+sum1)/N
}

extern "C" void kernel_launch(void* const* d_in, const int* in_sizes, int n_in,
                              void* d_out, int out_size, void* d_ws, size_t ws_size,
                              hipStream_t stream) {
    const float* pred = (const float*)d_in[0];
    const float* gt   = (const float*)d_in[1];
    float* out        = (float*)d_out;
    unsigned int* mins = (unsigned int*)d_ws;  // 2*NPTS uints = 128 KB

    hipLaunchKernelGGL(init_mins, dim3((2 * NPTS + 255) / 256), dim3(256), 0, stream,
                       mins, out);
    hipLaunchKernelGGL(chamfer_min, dim3(NXB, NSEG, 2), dim3(BLOCK), 0, stream,
                       pred, gt, mins);
    hipLaunchKernelGGL(chamfer_reduce, dim3(64), dim3(256), 0, stream, mins, out);
}